// Round 9
// baseline (99.071 us; speedup 1.0000x reference)
//
#include <hip/hip_runtime.h>

// VQ color lookup, round 19: VOP2-encoding probe (fmac/min vs fma/min3).
// R18 post-mortem: scalar-VOP3 (44.3us) LOSES to pk (40.5-40.9) -> pk@8
// theory dead. But all rounds sit at 2.2-2.6x the 2cyc-census: R18 busy
// (78% x 44 = 34.5us) ~ 2x the 17us census. Unified fit across R15/R16/
// R18: wave64 VOP3 ~4-4.5cyc, VOP3P ~8-9cyc (m07's measured 103 TF vs 157
// spec = ~3cyc even peak-tuned). Every inner-loop op we've ever issued is
// VOP3/VOP3P. Untested quadrant: VOP2. This round recodes the score as
//   v_fma (VOP3, 1) + v_fmac x2 (VOP2) + v_add (VOP2, cw+m commuted)
// and the select tree as 4x v_min_f32 (VOP2) -- bit-identical numerics
// (fmac == fma rounding; fp add commutes bitwise; min exact in any order;
// +-0 ties are == -transparent to resolve). Asm is tiny, single "s" INPUT
// floats only (not R17's 16-wide "=s" tuple outputs); chassis = R18
// (passed, clean counters), launch_bounds (256,4), ONE variable changed.
// If VOP2@2cyc real: vq 44 -> 33-37. If parity: encoding-independent VALU
// wall confirmed -> R20 pivots to MFMA or closes at R16.

#define KPAL 512
#define HW   65536            // 256*256
#define CHW  (3 * HW)
#define NPIX (8 * HW)         // 524288 pixels
#define NELEM (NPIX * 3)      // 1572864 output color elements
#define PPT   4               // pixels per thread (64 lanes * 4 = 256 px/block)
#define NWAVE 4
#define PAIRS_PER_WAVE (KPAL / 2 / NWAVE)   // 64
#define GROUPS_PER_WAVE (PAIRS_PER_WAVE / 2) // 32 (2 pairs = 4 entries each)

typedef float f2 __attribute__((ext_vector_type(2)));

struct __align__(32) Pair {   // palette entries 2j (lo half) and 2j+1 (hi)
    f2 x, y, z, w;            // x,y,z = NEGATED color; w = 0.5 * ||t||^2
};

__device__ Pair g_pairs[KPAL / 2];          // 8 KB static device memory

// Pack the negated pair table; zero the loss accumulator.
__global__ void prep_kernel(const float* __restrict__ table,
                            float* __restrict__ loss)
{
    const int j = threadIdx.x;            // 0..255
    if (j == 0) *loss = 0.0f;
    const float a0 = table[6 * j + 0], a1 = table[6 * j + 1], a2 = table[6 * j + 2];
    const float b0 = table[6 * j + 3], b1 = table[6 * j + 4], b2 = table[6 * j + 5];
    float aw, bw;
    {
#pragma clang fp contract(off)
        aw = a0 * a0 + a1 * a1 + a2 * a2;
        bw = b0 * b0 + b1 * b1 + b2 * b2;
    }
    Pair p;
    p.x = (f2){-a0, -b0};
    p.y = (f2){-a1, -b1};
    p.z = (f2){-a2, -b2};
    p.w = (f2){0.5f * aw, 0.5f * bw};     // exact
    g_pairs[j] = p;
}

// Score via VOP2-heavy encoding, bit-identical to the fmaf chain:
//   d = v_fma(nx, z0, hz); d += ny*z1 (v_fmac); d += nz*z2 (v_fmac);
//   d = cw + d (v_add, commuted -- fp add is bitwise commutative).
// Each instruction reads exactly one SGPR (constant-bus legal).
static __device__ __forceinline__ float entry_score_v2(
    float nx, float ny, float nz, float cw,
    float z0, float z1, float z2, float hz)
{
    float d;
    asm("v_fma_f32 %0, %1, %2, %3" : "=v"(d) : "s"(nx), "v"(z0), "v"(hz));
    asm("v_fmac_f32 %0, %1, %2" : "+v"(d) : "s"(ny), "v"(z1));
    asm("v_fmac_f32 %0, %1, %2" : "+v"(d) : "s"(nz), "v"(z2));
    asm("v_add_f32 %0, %1, %0" : "+v"(d) : "s"(cw));
    return d;
}

// Exact min via VOP2 v_min_f32 (min is exact; order-free for finite data).
static __device__ __forceinline__ float min_v2(float a, float b)
{
    float d;
    asm("v_min_f32 %0, %1, %2" : "=v"(d) : "v"(a), "v"(b));
    return d;
}

// Reference formula for the resolve (bit-equal to entry_score_v2):
static __device__ __forceinline__ float entry_score(
    float nx, float ny, float nz, float cw,
    float z0, float z1, float z2, float hz)
{
#pragma clang fp contract(off)
    float m = fmaf(nx, z0, hz);
    m = fmaf(ny, z1, m);
    m = fmaf(nz, z2, m);
    return m + cw;
}

__global__ __launch_bounds__(256, 4)
void vq_kernel(const float* __restrict__ z,
               const float* __restrict__ table,
               float* __restrict__ out,
               float* __restrict__ loss)
{
    __shared__ float cb_best[NWAVE][256];   // 4 KB
    __shared__ int   cb_bi[NWAVE][256];     // 4 KB
    __shared__ float wsum[NWAVE];
    const Pair* __restrict__ pairs = g_pairs;
    const int t = threadIdx.x;
    const int w = t >> 6, lane = t & 63;
    const int wu = __builtin_amdgcn_readfirstlane(w);   // wave-uniform SGPR

    // Block covers 256 consecutive pixels; all 4 waves process the same px.
    const int blockbase = blockIdx.x * 256;
    const int b  = blockbase >> 16;           // blocks never straddle batch
    const int p0 = blockbase & (HW - 1);
    const int base0 = b * CHW + p0 + lane;    // pixel i at base0 + 64*i

    float Z0[PPT], Z1[PPT], Z2[PPT], HZ[PPT];
#pragma unroll
    for (int i = 0; i < PPT; ++i) {
        const int base = base0 + 64 * i;
        const float z0 = z[base];
        const float z1 = z[base + HW];
        const float z2 = z[base + 2 * HW];
        float zs;
        {
#pragma clang fp contract(off)
            zs = z0 * z0 + z1 * z1 + z2 * z2;
        }
        Z0[i] = z0; Z1[i] = z1; Z2[i] = z2;
        HZ[i] = 0.5f * zs;                    // exact halve
    }

    float best[PPT];
    int   bg[PPT];                            // global GROUP index (4 entries)
#pragma unroll
    for (int i = 0; i < PPT; ++i) { best[i] = 3.4e38f; bg[i] = wu * GROUPS_PER_WAVE; }

    // Wave w scans its palette quarter, 2 pairs (= one 4-entry group) per
    // step. pairs + uniform index -> compiler emits pipelined s_loads.
    const int pb2 = wu * PAIRS_PER_WAVE;      // first pair of this quarter

#pragma unroll 2
    for (int g = 0; g < GROUPS_PER_WAVE; ++g) {
        const Pair pa = pairs[pb2 + 2 * g];
        const Pair pbb = pairs[pb2 + 2 * g + 1];
        const int gv = wu * GROUPS_PER_WAVE + g;
#pragma unroll
        for (int i = 0; i < PPT; ++i) {
            const float s0 = entry_score_v2(pa.x.x,  pa.y.x,  pa.z.x,  pa.w.x,
                                            Z0[i], Z1[i], Z2[i], HZ[i]);
            const float s1 = entry_score_v2(pa.x.y,  pa.y.y,  pa.z.y,  pa.w.y,
                                            Z0[i], Z1[i], Z2[i], HZ[i]);
            const float s2 = entry_score_v2(pbb.x.x, pbb.y.x, pbb.z.x, pbb.w.x,
                                            Z0[i], Z1[i], Z2[i], HZ[i]);
            const float s3 = entry_score_v2(pbb.x.y, pbb.y.y, pbb.z.y, pbb.w.y,
                                            Z0[i], Z1[i], Z2[i], HZ[i]);
            // Exact min tree, all VOP2: min is exact, order-free (finite).
            float m01 = min_v2(s0, s1);
            float m23 = min_v2(s2, s3);
            float mg  = min_v2(m01, m23);
            const float mn = min_v2(mg, best[i]);
            const bool imp = mn < best[i];
            bg[i] = imp ? gv : bg[i];
            best[i] = mn;
        }
    }

    // Resolve the winning entry within the winning 4-entry group: recompute
    // all 4 scores (bit-equal chain); first == best -> numpy first-index
    // within the group.
#pragma unroll
    for (int i = 0; i < PPT; ++i) {
        const int g = bg[i];
        const Pair ca  = pairs[2 * g];        // per-lane gather, L1-hit (8 KB)
        const Pair cb2 = pairs[2 * g + 1];
        const float s0 = entry_score(ca.x.x,  ca.y.x,  ca.z.x,  ca.w.x,
                                     Z0[i], Z1[i], Z2[i], HZ[i]);
        const float s1 = entry_score(ca.x.y,  ca.y.y,  ca.z.y,  ca.w.y,
                                     Z0[i], Z1[i], Z2[i], HZ[i]);
        const float s2 = entry_score(cb2.x.x, cb2.y.x, cb2.z.x, cb2.w.x,
                                     Z0[i], Z1[i], Z2[i], HZ[i]);
        const int m4 = (s0 == best[i]) ? 0 : (s1 == best[i]) ? 1
                     : (s2 == best[i]) ? 2 : 3;
        cb_best[w][lane + 64 * i] = best[i];
        cb_bi[w][lane + 64 * i]   = 4 * g + m4;
    }
    __syncthreads();

    // Combine quarters (ordered strict < => numpy first-index), write, loss.
    // px p = t was scanned by THIS thread at slot i == w: reuse regs, no z re-read.
    float z0s = Z0[0], z1s = Z1[0], z2s = Z2[0];
    if (w == 1)      { z0s = Z0[1]; z1s = Z1[1]; z2s = Z2[1]; }
    else if (w == 2) { z0s = Z0[2]; z1s = Z1[2]; z2s = Z2[2]; }
    else if (w == 3) { z0s = Z0[3]; z1s = Z1[3]; z2s = Z2[3]; }

    float lsum = 0.0f;
    {
        const int p = t;                      // 0..255 within block
        float bb = cb_best[0][p];
        int   kk = cb_bi[0][p];
#pragma unroll
        for (int ww = 1; ww < NWAVE; ++ww) {
            const float d  = cb_best[ww][p];
            const int   k2 = cb_bi[ww][p];
            if (d < bb) { bb = d; kk = k2; }
        }
        const int base = b * CHW + p0 + p;
        const float c0 = table[3 * kk + 0];
        const float c1 = table[3 * kk + 1];
        const float c2 = table[3 * kk + 2];
        out[base]          = c0;
        out[base + HW]     = c1;
        out[base + 2 * HW] = c2;
        const float e0 = c0 - z0s, e1 = c1 - z1s, e2 = c2 - z2s;
        lsum = e0 * e0 + e1 * e1 + e2 * e2;
    }

    for (int off = 32; off > 0; off >>= 1)
        lsum += __shfl_down(lsum, off);

    if ((t & 63) == 0) wsum[w] = lsum;
    __syncthreads();
    if (t == 0) {
        const float s = wsum[0] + wsum[1] + wsum[2] + wsum[3];
        atomicAdd(loss, s * (11.0f / (float)NELEM));
    }
}

extern "C" void kernel_launch(void* const* d_in, const int* in_sizes, int n_in,
                              void* d_out, int out_size, void* d_ws, size_t ws_size,
                              hipStream_t stream)
{
    const float* z     = (const float*)d_in[0];
    const float* table = (const float*)d_in[1];
    float* out  = (float*)d_out;
    float* loss = out + NELEM;

    prep_kernel<<<1, 256, 0, stream>>>(table, loss);
    vq_kernel<<<NPIX / 256, 256, 0, stream>>>(z, table, out, loss);
}

// Round 10
// 91.833 us; speedup vs baseline: 1.0788x; 1.0788x over previous
//
#include <hip/hip_runtime.h>

// VQ color lookup, round 20: PPT 4->8 -- amortize SMEM fences 2x.
// R19 post-mortem closed the encoding question via busy-time: pk 22.5us
// busy vs scalar 34.5 vs VOP2 37.5 -> VOP3P issues 4cyc like VOP3 but does
// 2x f32/inst; pk version does least VALU work AND idles 45% (fence
// stalls: lgkmcnt(0) drain per 2 group-steps, only ~192cyc cover vs
// ~200cyc K$ latency). R18/19 hid latency (busy 78-81%) but paid 1.7x
// insts. This round: pk math + 2x compute per fence. PPT=8: block = 512
// px (1024 blocks), per fence interval ~768 cyc of pk+select -> SMEM
// latency fully hidden, fences/px halved. quad_dist_s blob called twice
// per pair (px 0-3, 4-7). Numerics bitwise R16 (absmax 0.0 verified):
// same score blob, same fminf tree select, strict-< first-index combine,
// bitwise scalar resolve. Epilogue reuse: px t = slot w, px t+256 = slot
// w+4 of the same thread. VGPR est ~90 (cap 128 via (256,4)).

#define KPAL 512
#define HW   65536            // 256*256
#define CHW  (3 * HW)
#define NPIX (8 * HW)         // 524288 pixels
#define NELEM (NPIX * 3)      // 1572864 output color elements
#define PPT   8               // pixels per thread (64 lanes * 8 = 512 px/block)
#define BLKPX (64 * PPT)      // 512
#define NWAVE 4
#define PAIRS_PER_WAVE (KPAL / 2 / NWAVE)   // 64
#define GROUPS_PER_WAVE (PAIRS_PER_WAVE / 2) // 32 (2 pairs = 4 entries each)

typedef float f2   __attribute__((ext_vector_type(2)));
typedef float f16v __attribute__((ext_vector_type(16)));

struct __align__(32) Pair {   // palette entries 2j (lo half) and 2j+1 (hi)
    f2 x, y, z, w;            // x,y,z = NEGATED color; w = 0.5 * ||t||^2
};

__device__ Pair g_pairs[KPAL / 2];          // 8 KB static device memory

// Pack the negated pair table; zero the loss accumulator.
__global__ void prep_kernel(const float* __restrict__ table,
                            float* __restrict__ loss)
{
    const int j = threadIdx.x;            // 0..255
    if (j == 0) *loss = 0.0f;
    const float a0 = table[6 * j + 0], a1 = table[6 * j + 1], a2 = table[6 * j + 2];
    const float b0 = table[6 * j + 3], b1 = table[6 * j + 4], b2 = table[6 * j + 5];
    float aw, bw;
    {
#pragma clang fp contract(off)
        aw = a0 * a0 + a1 * a1 + a2 * a2;
        bw = b0 * b0 + b1 * b1 + b2 * b2;
    }
    Pair p;
    p.x = (f2){-a0, -b0};
    p.y = (f2){-a1, -b1};
    p.z = (f2){-a2, -b2};
    p.w = (f2){0.5f * aw, 0.5f * bw};     // exact
    g_pairs[j] = p;
}

// 4 pixels x 1 palette pair (R13-exact numerics):
//   d = fma(nz, z2, fma(ny, z1, fma(nx, z0, hz))) + cw
// nx,ny,nz,cw are SGPR pairs (one per instr -> constant-bus legal).
// ZA=(z0,z1), ZB=(z2,hz); op_sel broadcasts the pixel component and hz.
static __device__ __forceinline__ void quad_dist_s(
    f2 nx, f2 ny, f2 nz, f2 cw,
    f2 A0, f2 B0, f2 A1, f2 B1, f2 A2, f2 B2, f2 A3, f2 B3,
    f2& r0, f2& r1, f2& r2, f2& r3)
{
    f2 d0, d1, d2, d3;
    asm("v_pk_fma_f32 %[d0], %[nx], %[A0], %[B0] op_sel:[0,0,1] op_sel_hi:[1,0,1]\n\t"
        "v_pk_fma_f32 %[d1], %[nx], %[A1], %[B1] op_sel:[0,0,1] op_sel_hi:[1,0,1]\n\t"
        "v_pk_fma_f32 %[d2], %[nx], %[A2], %[B2] op_sel:[0,0,1] op_sel_hi:[1,0,1]\n\t"
        "v_pk_fma_f32 %[d3], %[nx], %[A3], %[B3] op_sel:[0,0,1] op_sel_hi:[1,0,1]\n\t"
        "v_pk_fma_f32 %[d0], %[ny], %[A0], %[d0] op_sel:[0,1,0] op_sel_hi:[1,1,1]\n\t"
        "v_pk_fma_f32 %[d1], %[ny], %[A1], %[d1] op_sel:[0,1,0] op_sel_hi:[1,1,1]\n\t"
        "v_pk_fma_f32 %[d2], %[ny], %[A2], %[d2] op_sel:[0,1,0] op_sel_hi:[1,1,1]\n\t"
        "v_pk_fma_f32 %[d3], %[ny], %[A3], %[d3] op_sel:[0,1,0] op_sel_hi:[1,1,1]\n\t"
        "v_pk_fma_f32 %[d0], %[nz], %[B0], %[d0] op_sel:[0,0,0] op_sel_hi:[1,0,1]\n\t"
        "v_pk_fma_f32 %[d1], %[nz], %[B1], %[d1] op_sel:[0,0,0] op_sel_hi:[1,0,1]\n\t"
        "v_pk_fma_f32 %[d2], %[nz], %[B2], %[d2] op_sel:[0,0,0] op_sel_hi:[1,0,1]\n\t"
        "v_pk_fma_f32 %[d3], %[nz], %[B3], %[d3] op_sel:[0,0,0] op_sel_hi:[1,0,1]\n\t"
        "v_pk_add_f32 %[d0], %[d0], %[cw]\n\t"
        "v_pk_add_f32 %[d1], %[d1], %[cw]\n\t"
        "v_pk_add_f32 %[d2], %[d2], %[cw]\n\t"
        "v_pk_add_f32 %[d3], %[d3], %[cw]"
        : [d0] "=&v"(d0), [d1] "=&v"(d1), [d2] "=&v"(d2), [d3] "=&v"(d3)
        : [A0] "v"(A0), [B0] "v"(B0), [A1] "v"(A1), [B1] "v"(B1),
          [A2] "v"(A2), [B2] "v"(B2), [A3] "v"(A3), [B3] "v"(B3),
          [nx] "s"(nx), [ny] "s"(ny), [nz] "s"(nz), [cw] "s"(cw));
    r0 = d0; r1 = d1; r2 = d2; r3 = d3;
}

// One s_load_dwordx16 (two Pairs = one 4-entry group) into an SGPR 16-tuple.
#define SLOAD2(dst, off) \
    asm volatile("s_load_dwordx16 %0, %1, %2" : "=s"(dst) : "s"(pairs), "s"(off))
// Drain SMEM; tie both waited buffers so extraction can't hoist past it.
#define SFENCE2(d1, d2) \
    asm volatile("s_waitcnt lgkmcnt(0)" : "+s"(d1), "+s"(d2))

__global__ __launch_bounds__(256, 4)
void vq_kernel(const float* __restrict__ z,
               const float* __restrict__ table,
               float* __restrict__ out,
               float* __restrict__ loss)
{
    __shared__ float cb_best[NWAVE][BLKPX]; // 8 KB
    __shared__ int   cb_bi[NWAVE][BLKPX];   // 8 KB
    __shared__ float wsum[NWAVE];
    const Pair* __restrict__ pairs = g_pairs;
    const int t = threadIdx.x;
    const int w = t >> 6, lane = t & 63;
    const int wu = __builtin_amdgcn_readfirstlane(w);   // wave-uniform SGPR

    // Block covers 512 consecutive pixels; all 4 waves process the same px.
    const int blockbase = blockIdx.x * BLKPX;
    const int b  = blockbase >> 16;           // blocks never straddle batch
    const int p0 = blockbase & (HW - 1);
    const int base0 = b * CHW + p0 + lane;    // pixel i at base0 + 64*i

    f2 ZA[PPT], ZB[PPT];                      // (z0,z1), (z2, 0.5*||z||^2)
#pragma unroll
    for (int i = 0; i < PPT; ++i) {
        const int base = base0 + 64 * i;
        const float z0 = z[base];
        const float z1 = z[base + HW];
        const float z2 = z[base + 2 * HW];
        float zs;
        {
#pragma clang fp contract(off)
            zs = z0 * z0 + z1 * z1 + z2 * z2;
        }
        ZA[i] = (f2){z0, z1};
        ZB[i] = (f2){z2, 0.5f * zs};          // exact halve
    }

    float best[PPT];
    int   bg[PPT];                            // global GROUP index (4 entries)
#pragma unroll
    for (int i = 0; i < PPT; ++i) { best[i] = 3.4e38f; bg[i] = wu * GROUPS_PER_WAVE; }

    // Wave w scans its palette quarter; one x16 load = one 4-entry group.
    const unsigned wbase = (unsigned)(wu * PAIRS_PER_WAVE) * 32u;

    // One group = 2 pairs from one x16 buffer; 8 px via two 4-px blob calls
    // per pair. Tree select (exact): mn = min3(min3(best, ra.x, ra.y),
    // rb.x, rb.y); strict < keeps earlier group -> first-index at group level.
#define GROUP_STEP(V, G)                                                     \
    do {                                                                     \
        const f2 nx0 = (f2){(V)[0], (V)[1]};                                 \
        const f2 ny0 = (f2){(V)[2], (V)[3]};                                 \
        const f2 nz0 = (f2){(V)[4], (V)[5]};                                 \
        const f2 cw0 = (f2){(V)[6], (V)[7]};                                 \
        const f2 nx1 = (f2){(V)[8], (V)[9]};                                 \
        const f2 ny1 = (f2){(V)[10], (V)[11]};                               \
        const f2 nz1 = (f2){(V)[12], (V)[13]};                               \
        const f2 cw1 = (f2){(V)[14], (V)[15]};                               \
        f2 ra[PPT], rb[PPT];                                                 \
        quad_dist_s(nx0, ny0, nz0, cw0,                                      \
                    ZA[0], ZB[0], ZA[1], ZB[1], ZA[2], ZB[2], ZA[3], ZB[3],  \
                    ra[0], ra[1], ra[2], ra[3]);                             \
        quad_dist_s(nx0, ny0, nz0, cw0,                                      \
                    ZA[4], ZB[4], ZA[5], ZB[5], ZA[6], ZB[6], ZA[7], ZB[7],  \
                    ra[4], ra[5], ra[6], ra[7]);                             \
        quad_dist_s(nx1, ny1, nz1, cw1,                                      \
                    ZA[0], ZB[0], ZA[1], ZB[1], ZA[2], ZB[2], ZA[3], ZB[3],  \
                    rb[0], rb[1], rb[2], rb[3]);                             \
        quad_dist_s(nx1, ny1, nz1, cw1,                                      \
                    ZA[4], ZB[4], ZA[5], ZB[5], ZA[6], ZB[6], ZA[7], ZB[7],  \
                    rb[4], rb[5], rb[6], rb[7]);                             \
        const int gv = (G);                                                  \
        _Pragma("unroll")                                                    \
        for (int i = 0; i < PPT; ++i) {                                      \
            const float m1 = fminf(fminf(best[i], ra[i].x), ra[i].y);        \
            const float mn = fminf(fminf(m1, rb[i].x), rb[i].y);             \
            const bool imp = mn < best[i];                                   \
            bg[i] = imp ? gv : bg[i];                                        \
            best[i] = mn;                                                    \
        }                                                                    \
    } while (0)

    {
        f16v A1, A2, B1, B2;
        SLOAD2(A1, wbase);                                // groups 0,1
        SLOAD2(A2, wbase + 64u);
#pragma unroll 1
        for (int c = 0; c < PAIRS_PER_WAVE; c += 8) {     // 8 pairs = 4 groups
            const int g0 = wu * GROUPS_PER_WAVE + (c >> 1);
            SFENCE2(A1, A2);                              // only A1,A2 were outstanding
            SLOAD2(B1, wbase + (unsigned)(c + 4) * 32u);  // hide under 2 group-steps
            SLOAD2(B2, wbase + (unsigned)(c + 6) * 32u);
            GROUP_STEP(A1, g0);
            GROUP_STEP(A2, g0 + 1);
            SFENCE2(B1, B2);                              // only B1,B2 outstanding
            if (c + 8 < PAIRS_PER_WAVE) {
                SLOAD2(A1, wbase + (unsigned)(c + 8) * 32u);
                SLOAD2(A2, wbase + (unsigned)(c + 10) * 32u);
            }
            GROUP_STEP(B1, g0 + 2);
            GROUP_STEP(B2, g0 + 3);
        }
    }
#undef GROUP_STEP

    // Resolve the winning entry within the winning 4-entry group: recompute
    // all 4 scores with scalar chains that replicate the pk lanes BITWISE
    // (v_pk_fma lane == fmaf, v_pk_add lane == scalar add); first == best
    // -> numpy first-index within the group.
#pragma unroll
    for (int i = 0; i < PPT; ++i) {
        const int g = bg[i];
        const Pair ca = pairs[2 * g];         // per-lane gather, L1-hit (8 KB)
        const Pair cb2 = pairs[2 * g + 1];
        float s0, s1, s2, s3;
        {
#pragma clang fp contract(off)
            float m;
            m = fmaf(ca.x.x, ZA[i].x, ZB[i].y);
            m = fmaf(ca.y.x, ZA[i].y, m);
            m = fmaf(ca.z.x, ZB[i].x, m);
            s0 = m + ca.w.x;
            m = fmaf(ca.x.y, ZA[i].x, ZB[i].y);
            m = fmaf(ca.y.y, ZA[i].y, m);
            m = fmaf(ca.z.y, ZB[i].x, m);
            s1 = m + ca.w.y;
            m = fmaf(cb2.x.x, ZA[i].x, ZB[i].y);
            m = fmaf(cb2.y.x, ZA[i].y, m);
            m = fmaf(cb2.z.x, ZB[i].x, m);
            s2 = m + cb2.w.x;
            m = fmaf(cb2.x.y, ZA[i].x, ZB[i].y);
            m = fmaf(cb2.y.y, ZA[i].y, m);
            m = fmaf(cb2.z.y, ZB[i].x, m);
            s3 = m + cb2.w.y;
        }
        const int m4 = (s0 == best[i]) ? 0 : (s1 == best[i]) ? 1
                     : (s2 == best[i]) ? 2 : 3;
        cb_best[w][lane + 64 * i] = best[i];
        cb_bi[w][lane + 64 * i]   = 4 * g + m4;
    }
    __syncthreads();

    // Combine quarters (ordered strict < => numpy first-index), write, loss.
    // Thread t combines px t (= its slot w) and px t+256 (= its slot w+4):
    // reuse regs, no z re-read.
    float lsum = 0.0f;
#pragma unroll
    for (int half = 0; half < 2; ++half) {
        const int p = t + 256 * half;         // 0..511 within block
        const int slot = w + 4 * half;
        const f2 zA = ZA[slot], zB = ZB[slot];
        float bb = cb_best[0][p];
        int   kk = cb_bi[0][p];
#pragma unroll
        for (int ww = 1; ww < NWAVE; ++ww) {
            const float d  = cb_best[ww][p];
            const int   k2 = cb_bi[ww][p];
            if (d < bb) { bb = d; kk = k2; }
        }
        const int base = b * CHW + p0 + p;
        const float c0 = table[3 * kk + 0];
        const float c1 = table[3 * kk + 1];
        const float c2 = table[3 * kk + 2];
        out[base]          = c0;
        out[base + HW]     = c1;
        out[base + 2 * HW] = c2;
        const float e0 = c0 - zA.x, e1 = c1 - zA.y, e2 = c2 - zB.x;
        lsum += e0 * e0 + e1 * e1 + e2 * e2;
    }

    for (int off = 32; off > 0; off >>= 1)
        lsum += __shfl_down(lsum, off);

    if ((t & 63) == 0) wsum[w] = lsum;
    __syncthreads();
    if (t == 0) {
        const float s = wsum[0] + wsum[1] + wsum[2] + wsum[3];
        atomicAdd(loss, s * (11.0f / (float)NELEM));
    }
}

extern "C" void kernel_launch(void* const* d_in, const int* in_sizes, int n_in,
                              void* d_out, int out_size, void* d_ws, size_t ws_size,
                              hipStream_t stream)
{
    const float* z     = (const float*)d_in[0];
    const float* table = (const float*)d_in[1];
    float* out  = (float*)d_out;
    float* loss = out + NELEM;

    prep_kernel<<<1, 256, 0, stream>>>(table, loss);
    vq_kernel<<<NPIX / BLKPX, 256, 0, stream>>>(z, table, out, loss);
}